// Round 5
// baseline (677.962 us; speedup 1.0000x reference)
//
#include <hip/hip_runtime.h>
#include <hip/hip_bf16.h>
#include <math.h>

typedef __bf16 bf16x8 __attribute__((ext_vector_type(8)));
typedef float  f32x4  __attribute__((ext_vector_type(4)));

#define MFMA16 __builtin_amdgcn_mfma_f32_16x16x32_bf16

__device__ __forceinline__ float silu_f(float v) {
    return v * __builtin_amdgcn_rcpf(1.0f + __expf(-v));
}

// LDS weight layout: Wt[j][k], bf16, 16B-chunk XOR swizzle:
// phys = j*K + (((k>>3) ^ (j&7))<<3) + (k&7)  -> ds_read_b128, 2-way max.

// ---- detector: is edge_index stored as int64 (odd words all zero)? ---------
__global__ void k_detect(const int* __restrict__ ei, int* __restrict__ flag) {
    __shared__ int red[256];
    int v = 0;
#pragma unroll
    for (int j = 0; j < 4; ++j) v |= ei[2 * (threadIdx.x * 4 + j) + 1];
    red[threadIdx.x] = v;
    __syncthreads();
    for (int s = 128; s > 0; s >>= 1) {
        if (threadIdx.x < s) red[threadIdx.x] |= red[threadIdx.x + s];
        __syncthreads();
    }
    if (threadIdx.x == 0) *flag = (red[0] == 0) ? 1 : 0;
}

// ---- CSR build --------------------------------------------------------------
__global__ __launch_bounds__(256) void k_hist(
    const int* __restrict__ ei, const int* __restrict__ flag,
    int* __restrict__ counts, int E)
{
    int e = blockIdx.x * 256 + threadIdx.x;
    if (e >= E) return;
    const int is64 = *flag;
    int r = is64 ? ei[2 * E + 2 * e] : ei[E + e];
    atomicAdd(&counts[r], 1);
}

__global__ __launch_bounds__(256) void k_scan1(
    const int* __restrict__ counts, int* __restrict__ offsets,
    int* __restrict__ partials, int N)
{
    __shared__ int pairv[256];
    __shared__ int buf[256];
    const int t = threadIdx.x;
    const int base = blockIdx.x * 512;
    int a = (base + 2 * t     < N) ? counts[base + 2 * t]     : 0;
    int b = (base + 2 * t + 1 < N) ? counts[base + 2 * t + 1] : 0;
    pairv[t] = a + b;
    buf[t]   = a + b;
    __syncthreads();
    for (int d = 1; d < 256; d <<= 1) {
        int v = buf[t];
        int w = (t >= d) ? buf[t - d] : 0;
        __syncthreads();
        buf[t] = v + w;
        __syncthreads();
    }
    int excl = buf[t] - pairv[t];
    if (base + 2 * t     < N) offsets[base + 2 * t]     = excl;
    if (base + 2 * t + 1 < N) offsets[base + 2 * t + 1] = excl + a;
    if (t == 255) partials[blockIdx.x] = buf[255];
}

__global__ void k_scan2(int* __restrict__ partials, int nblk) {
    __shared__ int buf[256];
    const int t = threadIdx.x;
    int v0 = (t < nblk) ? partials[t] : 0;
    buf[t] = v0;
    __syncthreads();
    for (int d = 1; d < 256; d <<= 1) {
        int v = buf[t];
        int w = (t >= d) ? buf[t - d] : 0;
        __syncthreads();
        buf[t] = v + w;
        __syncthreads();
    }
    if (t < nblk) partials[t] = buf[t] - v0;   // exclusive
}

__global__ __launch_bounds__(256) void k_scan3(
    int* __restrict__ offsets, const int* __restrict__ partials,
    int* __restrict__ cursor, int N)
{
    int i = blockIdx.x * 256 + threadIdx.x;
    if (i >= N) return;
    int v = offsets[i] + partials[i >> 9];
    offsets[i] = v;
    cursor[i]  = v;
}

__global__ __launch_bounds__(256) void k_scatter(
    const int* __restrict__ ei, const int* __restrict__ flag,
    int* __restrict__ cursor, int* __restrict__ csr_s, int E)
{
    int e = blockIdx.x * 256 + threadIdx.x;
    if (e >= E) return;
    const int is64 = *flag;
    int s, r;
    if (is64) { s = ei[2 * e]; r = ei[2 * E + 2 * e]; }
    else      { s = ei[e];     r = ei[E + e];         }
    int slot = atomicAdd(&cursor[r], 1);
    csr_s[slot] = s;
}

// ---- phase 1: AB[n][0:128]=bf16(x@W1a + b1), AB[n][128:256]=bf16(x@W1b) ----
__global__ __launch_bounds__(256) void k_node1(
    const float* __restrict__ x, const float* __restrict__ W1,
    const float* __restrict__ b1, __bf16* __restrict__ AB, int N, int ngroups)
{
    __shared__ __bf16 wt[256 * 128];
    for (int idx = threadIdx.x; idx < 256 * 128; idx += 256) {
        int j = idx & 255, k = idx >> 8;
        float w = (j < 128) ? W1[(k << 7) + j] : W1[((k + 128) << 7) + (j - 128)];
        wt[(j << 7) + ((((k >> 3) ^ (j & 7))) << 3) + (k & 7)] = (__bf16)w;
    }
    __syncthreads();

    const int lane = threadIdx.x & 63;
    const int row  = lane & 15;
    const int kq   = lane >> 4;

    for (int g = blockIdx.x; g < ngroups; g += gridDim.x) {
        const int row0 = g * 64 + (threadIdx.x >> 6) * 16;
        int m = row0 + row; if (m >= N) m = N - 1;
        const float* xr = x + (size_t)m * 128;

        bf16x8 afr[4];
#pragma unroll
        for (int c = 0; c < 4; ++c) {
            const int k0 = c * 32 + kq * 8;
            float4 a0 = *(const float4*)(xr + k0);
            float4 a1 = *(const float4*)(xr + k0 + 4);
            bf16x8 af;
            af[0]=(__bf16)a0.x; af[1]=(__bf16)a0.y; af[2]=(__bf16)a0.z; af[3]=(__bf16)a0.w;
            af[4]=(__bf16)a1.x; af[5]=(__bf16)a1.y; af[6]=(__bf16)a1.z; af[7]=(__bf16)a1.w;
            afr[c] = af;
        }

        f32x4 acc[16] = {};
#pragma unroll
        for (int t = 0; t < 16; ++t) {
            const int j  = t * 16 + row;
            const int jb = j & 7;
            const __bf16* base = wt + (j << 7);
#pragma unroll
            for (int c = 0; c < 4; ++c) {
                const int kb = c * 4 + kq;
                bf16x8 b = *(const bf16x8*)(base + ((kb ^ jb) << 3));
                acc[t] = MFMA16(afr[c], b, acc[t], 0, 0, 0);
            }
        }

#pragma unroll
        for (int t = 0; t < 16; ++t) {
            const int col = t * 16 + row;
            const float bb = (col < 128) ? b1[col] : 0.0f;
#pragma unroll
            for (int q = 0; q < 4; ++q) {
                const int gr = row0 + kq * 4 + q;
                if (gr < N) AB[(size_t)gr * 256 + col] = (__bf16)(acc[t][q] + bb);
            }
        }
    }
}

// ---- phase 2 (CSR): wave-per-receiver, atomic-free aggregation -------------
__global__ __launch_bounds__(256) void k_edge_csr(
    const __bf16* __restrict__ AB, const float* __restrict__ pos,
    const int* __restrict__ csr_s, const int* __restrict__ offsets,
    const int* __restrict__ counts, const float* __restrict__ W2,
    const float* __restrict__ b2, const float* __restrict__ w3,
    float* __restrict__ aggr, int N)
{
    __shared__ __bf16 wt[128 * 128];
    for (int idx = threadIdx.x; idx < 128 * 128; idx += 256) {
        int j = idx & 127, k = idx >> 7;
        wt[(j << 7) + ((((k >> 3) ^ (j & 7))) << 3) + (k & 7)] = (__bf16)W2[(k << 7) + j];
    }
    __syncthreads();

    const int lane = threadIdx.x & 63;
    const int row  = lane & 15;
    const int kq   = lane >> 4;
    const int r    = blockIdx.x * 4 + (threadIdx.x >> 6);
    if (r >= N) return;

    const int off = offsets[r];
    const int deg = counts[r];

    const float prx = pos[3 * r], pry = pos[3 * r + 1], prz = pos[3 * r + 2];
    bf16x8 bvr[4];
#pragma unroll
    for (int c = 0; c < 4; ++c)
        bvr[c] = *(const bf16x8*)(AB + (size_t)r * 256 + 128 + c * 32 + kq * 8);

    float b2c[8];
#pragma unroll
    for (int t = 0; t < 8; ++t) b2c[t] = b2[t * 16 + row];

    float colacc[8] = {0, 0, 0, 0, 0, 0, 0, 0};

    const int ntile = (deg + 15) >> 4;
    for (int tile = 0; tile < ntile; ++tile) {
        const int el    = tile * 16 + row;
        const int idx   = off + ((el < deg) ? el : (deg - 1));
        const int s     = csr_s[idx];

        const float dx = pos[3 * s]     - prx;
        const float dy = pos[3 * s + 1] - pry;
        const float dz = pos[3 * s + 2] - prz;
        const float d  = sqrtf(dx * dx + dy * dy + dz * dz);

        const __bf16* Ar = AB + (size_t)s * 256;
        bf16x8 afr[4];
#pragma unroll
        for (int c = 0; c < 4; ++c) {
            const int k0 = c * 32 + kq * 8;
            bf16x8 a = *(const bf16x8*)(Ar + k0);
            bf16x8 bb = bvr[c];
            float4 w0 = *(const float4*)(w3 + k0);
            float4 w1 = *(const float4*)(w3 + k0 + 4);
            bf16x8 af;
            af[0] = (__bf16)silu_f((float)a[0] + (float)bb[0] + d * w0.x);
            af[1] = (__bf16)silu_f((float)a[1] + (float)bb[1] + d * w0.y);
            af[2] = (__bf16)silu_f((float)a[2] + (float)bb[2] + d * w0.z);
            af[3] = (__bf16)silu_f((float)a[3] + (float)bb[3] + d * w0.w);
            af[4] = (__bf16)silu_f((float)a[4] + (float)bb[4] + d * w1.x);
            af[5] = (__bf16)silu_f((float)a[5] + (float)bb[5] + d * w1.y);
            af[6] = (__bf16)silu_f((float)a[6] + (float)bb[6] + d * w1.z);
            af[7] = (__bf16)silu_f((float)a[7] + (float)bb[7] + d * w1.w);
            afr[c] = af;
        }

        f32x4 acc[8] = {};
#pragma unroll
        for (int t = 0; t < 8; ++t) {
            const int j  = t * 16 + row;
            const int jb = j & 7;
            const __bf16* base = wt + (j << 7);
#pragma unroll
            for (int c = 0; c < 4; ++c) {
                const int kb = c * 4 + kq;
                bf16x8 b = *(const bf16x8*)(base + ((kb ^ jb) << 3));
                acc[t] = MFMA16(afr[c], b, acc[t], 0, 0, 0);
            }
        }

        // silu + masked accumulate (output row = edge kq*4+q, col = t*16+row)
#pragma unroll
        for (int t = 0; t < 8; ++t) {
#pragma unroll
            for (int q = 0; q < 4; ++q) {
                const int er = tile * 16 + kq * 4 + q;
                if (er < deg) colacc[t] += silu_f(acc[t][q] + b2c[t]);
            }
        }
    }

    // reduce across the 4 kq groups (rows 0..15 live in kq*4+q slots)
#pragma unroll
    for (int t = 0; t < 8; ++t) {
        float v = colacc[t];
        v += __shfl_xor(v, 16, 64);
        v += __shfl_xor(v, 32, 64);
        colacc[t] = v;
    }
    if (kq == 0) {
#pragma unroll
        for (int t = 0; t < 8; ++t)
            aggr[(size_t)r * 128 + t * 16 + row] = colacc[t];
    }
}

// ---- phase 2 fallback (round-3 atomic version, if ws too small) ------------
__global__ __launch_bounds__(256) void k_edge_fb(
    const __bf16* __restrict__ AB, const float* __restrict__ pos,
    const int* __restrict__ ei, const int* __restrict__ flag,
    const float* __restrict__ W2, const float* __restrict__ b2,
    const float* __restrict__ w3, float* __restrict__ aggr, int E, int ngroups)
{
    __shared__ __bf16 wt[128 * 128];
    for (int idx = threadIdx.x; idx < 128 * 128; idx += 256) {
        int j = idx & 127, k = idx >> 7;
        wt[(j << 7) + ((((k >> 3) ^ (j & 7))) << 3) + (k & 7)] = (__bf16)W2[(k << 7) + j];
    }
    __syncthreads();

    const int is64 = flag ? *flag : 0;
    const int lane = threadIdx.x & 63;
    const int row  = lane & 15;
    const int kq   = lane >> 4;

    for (int g = blockIdx.x; g < ngroups; g += gridDim.x) {
        const int e = g * 64 + (threadIdx.x >> 6) * 16 + row;
        int s, r;
        if (is64) { s = ei[2 * e]; r = ei[2 * E + 2 * e]; }
        else      { s = ei[e];     r = ei[E + e];         }
        float dx = pos[3 * s + 0] - pos[3 * r + 0];
        float dy = pos[3 * s + 1] - pos[3 * r + 1];
        float dz = pos[3 * s + 2] - pos[3 * r + 2];
        float d  = sqrtf(dx * dx + dy * dy + dz * dz);

        const __bf16* Arow = AB + (size_t)s * 256;
        const __bf16* Brow = AB + (size_t)r * 256 + 128;

        bf16x8 afr[4];
#pragma unroll
        for (int c = 0; c < 4; ++c) {
            const int k0 = c * 32 + kq * 8;
            bf16x8 av = *(const bf16x8*)(Arow + k0);
            bf16x8 bv = *(const bf16x8*)(Brow + k0);
            float4 w0 = *(const float4*)(w3 + k0);
            float4 w1 = *(const float4*)(w3 + k0 + 4);
            bf16x8 af;
            af[0] = (__bf16)silu_f((float)av[0] + (float)bv[0] + d * w0.x);
            af[1] = (__bf16)silu_f((float)av[1] + (float)bv[1] + d * w0.y);
            af[2] = (__bf16)silu_f((float)av[2] + (float)bv[2] + d * w0.z);
            af[3] = (__bf16)silu_f((float)av[3] + (float)bv[3] + d * w0.w);
            af[4] = (__bf16)silu_f((float)av[4] + (float)bv[4] + d * w1.x);
            af[5] = (__bf16)silu_f((float)av[5] + (float)bv[5] + d * w1.y);
            af[6] = (__bf16)silu_f((float)av[6] + (float)bv[6] + d * w1.z);
            af[7] = (__bf16)silu_f((float)av[7] + (float)bv[7] + d * w1.w);
            afr[c] = af;
        }

        f32x4 acc[8] = {};
#pragma unroll
        for (int t = 0; t < 8; ++t) {
            const int j  = t * 16 + row;
            const int jb = j & 7;
            const __bf16* base = wt + (j << 7);
#pragma unroll
            for (int c = 0; c < 4; ++c) {
                const int kb = c * 4 + kq;
                bf16x8 b = *(const bf16x8*)(base + ((kb ^ jb) << 3));
                acc[t] = MFMA16(afr[c], b, acc[t], 0, 0, 0);
            }
        }

        int rr[4];
#pragma unroll
        for (int q = 0; q < 4; ++q) rr[q] = __shfl(r, kq * 4 + q, 64);

#pragma unroll
        for (int t = 0; t < 8; ++t) {
            const int col = t * 16 + row;
            const float bb = b2[col];
#pragma unroll
            for (int q = 0; q < 4; ++q) {
                float v = silu_f(acc[t][q] + bb);
                unsafeAtomicAdd(aggr + (size_t)rr[q] * 128 + col, v);
            }
        }
    }
}

// -------- phase 3: u = silu(x@U1a + aggr@U1b + c1), bf16, IN PLACE over aggr
__global__ __launch_bounds__(256) void k_node2(
    const float* __restrict__ x, const float* __restrict__ aggr,
    const float* __restrict__ U1, const float* __restrict__ c1,
    __bf16* __restrict__ u, int N, int ngroups)
{
    __shared__ __bf16 wt[128 * 256];
    for (int idx = threadIdx.x; idx < 128 * 256; idx += 256) {
        int j = idx & 127, k = idx >> 7;
        wt[(j << 8) + ((((k >> 3) ^ (j & 7))) << 3) + (k & 7)] = (__bf16)U1[(k << 7) + j];
    }
    __syncthreads();

    const int lane = threadIdx.x & 63;
    const int row  = lane & 15;
    const int kq   = lane >> 4;

    for (int g = blockIdx.x; g < ngroups; g += gridDim.x) {
        const int row0 = g * 64 + (threadIdx.x >> 6) * 16;
        int m = row0 + row; if (m >= N) m = N - 1;

        bf16x8 afr[8];
#pragma unroll
        for (int c = 0; c < 8; ++c) {
            const int k0 = (c & 3) * 32 + kq * 8;
            const float* src = (c < 4) ? (x + (size_t)m * 128 + k0)
                                       : (aggr + (size_t)m * 128 + k0);
            float4 a0 = *(const float4*)(src);
            float4 a1 = *(const float4*)(src + 4);
            bf16x8 af;
            af[0]=(__bf16)a0.x; af[1]=(__bf16)a0.y; af[2]=(__bf16)a0.z; af[3]=(__bf16)a0.w;
            af[4]=(__bf16)a1.x; af[5]=(__bf16)a1.y; af[6]=(__bf16)a1.z; af[7]=(__bf16)a1.w;
            afr[c] = af;
        }

        f32x4 acc[8] = {};
#pragma unroll
        for (int t = 0; t < 8; ++t) {
            const int j  = t * 16 + row;
            const int jb = j & 7;
            const __bf16* base = wt + (j << 8);
#pragma unroll
            for (int c = 0; c < 8; ++c) {
                const int kb = c * 4 + kq;
                bf16x8 b = *(const bf16x8*)(base + ((kb ^ jb) << 3));
                acc[t] = MFMA16(afr[c], b, acc[t], 0, 0, 0);
            }
        }

#pragma unroll
        for (int t = 0; t < 8; ++t) {
            const int col = t * 16 + row;
            const float cc = c1[col];
#pragma unroll
            for (int q = 0; q < 4; ++q) {
                const int gr = row0 + kq * 4 + q;
                if (gr < N) u[(size_t)gr * 256 + col] = (__bf16)silu_f(acc[t][q] + cc);
            }
        }
    }
}

// ---------------- phase 4: out = u@U2 + c2 (overwrites AB in d_out) ---------
__global__ __launch_bounds__(256) void k_node3(
    const __bf16* __restrict__ u, const float* __restrict__ U2,
    const float* __restrict__ c2, float* __restrict__ out, int N, int ngroups)
{
    __shared__ __bf16 wt[128 * 128];
    for (int idx = threadIdx.x; idx < 128 * 128; idx += 256) {
        int j = idx & 127, k = idx >> 7;
        wt[(j << 7) + ((((k >> 3) ^ (j & 7))) << 3) + (k & 7)] = (__bf16)U2[(k << 7) + j];
    }
    __syncthreads();

    const int lane = threadIdx.x & 63;
    const int row  = lane & 15;
    const int kq   = lane >> 4;

    for (int g = blockIdx.x; g < ngroups; g += gridDim.x) {
        const int row0 = g * 64 + (threadIdx.x >> 6) * 16;
        int m = row0 + row; if (m >= N) m = N - 1;

        bf16x8 afr[4];
#pragma unroll
        for (int c = 0; c < 4; ++c) {
            const int k0 = c * 32 + kq * 8;
            afr[c] = *(const bf16x8*)(u + (size_t)m * 256 + k0);
        }

        f32x4 acc[8] = {};
#pragma unroll
        for (int t = 0; t < 8; ++t) {
            const int j  = t * 16 + row;
            const int jb = j & 7;
            const __bf16* base = wt + (j << 7);
#pragma unroll
            for (int c = 0; c < 4; ++c) {
                const int kb = c * 4 + kq;
                bf16x8 b = *(const bf16x8*)(base + ((kb ^ jb) << 3));
                acc[t] = MFMA16(afr[c], b, acc[t], 0, 0, 0);
            }
        }

#pragma unroll
        for (int t = 0; t < 8; ++t) {
            const int col = t * 16 + row;
            const float cc = c2[col];
#pragma unroll
            for (int q = 0; q < 4; ++q) {
                const int gr = row0 + kq * 4 + q;
                if (gr < N) out[(size_t)gr * 128 + col] = acc[t][q] + cc;
            }
        }
    }
}

extern "C" void kernel_launch(void* const* d_in, const int* in_sizes, int n_in,
                              void* d_out, int out_size, void* d_ws, size_t ws_size,
                              hipStream_t stream) {
    (void)n_in; (void)out_size;
    const float* x   = (const float*)d_in[0];
    const float* pos = (const float*)d_in[1];
    const int*   ei  = (const int*)d_in[2];
    const float* W1  = (const float*)d_in[3];
    const float* b1  = (const float*)d_in[4];
    const float* W2  = (const float*)d_in[5];
    const float* b2  = (const float*)d_in[6];
    const float* U1  = (const float*)d_in[7];
    const float* c1  = (const float*)d_in[8];
    const float* U2  = (const float*)d_in[9];
    const float* c2  = (const float*)d_in[10];

    const int N = in_sizes[0] / 128;
    const int E = in_sizes[2] / 2;

    // ---- workspace layout (16B-aligned slabs) ----
    const size_t aggr_b  = (size_t)N * 128 * sizeof(float);
    const size_t Ni_b    = (((size_t)N * 4) + 15) & ~(size_t)15;
    const size_t E_b     = (((size_t)E * 4) + 15) & ~(size_t)15;
    size_t off = 0;
    char* base = (char*)d_ws;
    float* aggr   = (float*)(base + off); off += aggr_b;
    int*   flag   = (int*)  (base + off); off += 16;
    int*   counts = (int*)  (base + off); off += Ni_b;
    int*   offs   = (int*)  (base + off); off += Ni_b;
    int*   cursor = (int*)  (base + off); off += Ni_b;
    int*   parts  = (int*)  (base + off); off += 256 * 4;
    int*   csr_s  = (int*)  (base + off); off += E_b;
    const size_t need_csr = off;

    __bf16* u  = (__bf16*)d_ws;        // row stride 256 elem, aliases aggr
    __bf16* AB = (__bf16*)d_out;       // N*256 bf16 == out_nbytes

    const int nblk_scan = (N + 511) / 512;
    const bool csr_ok = (ws_size >= need_csr) && (nblk_scan <= 256);

    if (ws_size < aggr_b + 16) return;   // cannot run at all

    const int ng_nodes = (N + 63) / 64;
    const int grid_n   = ng_nodes < 512 ? ng_nodes : 512;
    const int grid_E   = (E + 255) / 256;
    const int grid_Nt  = (N + 255) / 256;

    k_detect<<<1, 256, 0, stream>>>(ei, flag);
    k_node1<<<grid_n, 256, 0, stream>>>(x, W1, b1, AB, N, ng_nodes);

    if (csr_ok) {
        hipMemsetAsync(counts, 0, (size_t)N * 4, stream);
        k_hist   <<<grid_E, 256, 0, stream>>>(ei, flag, counts, E);
        k_scan1  <<<nblk_scan, 256, 0, stream>>>(counts, offs, parts, N);
        k_scan2  <<<1, 256, 0, stream>>>(parts, nblk_scan);
        k_scan3  <<<grid_Nt, 256, 0, stream>>>(offs, parts, cursor, N);
        k_scatter<<<grid_E, 256, 0, stream>>>(ei, flag, cursor, csr_s, E);
        k_edge_csr<<<(N + 3) / 4, 256, 0, stream>>>(
            AB, pos, csr_s, offs, counts, W2, b2, W1 + 256 * 128, aggr, N);
    } else {
        hipMemsetAsync(aggr, 0, aggr_b, stream);
        const int ng_edges = E / 64;
        const int grid_e   = ng_edges < 1250 ? ng_edges : 1250;
        k_edge_fb<<<grid_e, 256, 0, stream>>>(AB, pos, ei, flag, W2, b2,
                                              W1 + 256 * 128, aggr, E, ng_edges);
    }

    k_node2<<<grid_n, 256, 0, stream>>>(x, aggr, U1, c1, u, N, ng_nodes);
    k_node3<<<grid_n, 256, 0, stream>>>(u, U2, c2, (float*)d_out, N, ng_nodes);
}

// Round 6
// 539.983 us; speedup vs baseline: 1.2555x; 1.2555x over previous
//
#include <hip/hip_runtime.h>
#include <hip/hip_bf16.h>
#include <math.h>

typedef __bf16 bf16x8 __attribute__((ext_vector_type(8)));
typedef float  f32x4  __attribute__((ext_vector_type(4)));

#define MFMA16 __builtin_amdgcn_mfma_f32_16x16x32_bf16

__device__ __forceinline__ float silu_f(float v) {
    return v * __builtin_amdgcn_rcpf(1.0f + __expf(-v));
}

// LDS weight layout: Wt[j][k], bf16, 16B-chunk XOR swizzle:
// phys = j*K + (((k>>3) ^ (j&7))<<3) + (k&7)  -> ds_read_b128, 2-way max.

// ---- detector: is edge_index stored as int64 (odd words all zero)? ---------
__global__ void k_detect(const int* __restrict__ ei, int* __restrict__ flag) {
    __shared__ int red[256];
    int v = 0;
#pragma unroll
    for (int j = 0; j < 4; ++j) v |= ei[2 * (threadIdx.x * 4 + j) + 1];
    red[threadIdx.x] = v;
    __syncthreads();
    for (int s = 128; s > 0; s >>= 1) {
        if (threadIdx.x < s) red[threadIdx.x] |= red[threadIdx.x + s];
        __syncthreads();
    }
    if (threadIdx.x == 0) *flag = (red[0] == 0) ? 1 : 0;
}

// ---- CSR build --------------------------------------------------------------
__global__ __launch_bounds__(256) void k_hist(
    const int* __restrict__ ei, const int* __restrict__ flag,
    int* __restrict__ counts, int E)
{
    int e = blockIdx.x * 256 + threadIdx.x;
    if (e >= E) return;
    const int is64 = *flag;
    int r = is64 ? ei[2 * E + 2 * e] : ei[E + e];
    atomicAdd(&counts[r], 1);
}

__global__ __launch_bounds__(256) void k_scan1(
    const int* __restrict__ counts, int* __restrict__ offsets,
    int* __restrict__ partials, int N)
{
    __shared__ int pairv[256];
    __shared__ int buf[256];
    const int t = threadIdx.x;
    const int base = blockIdx.x * 512;
    int a = (base + 2 * t     < N) ? counts[base + 2 * t]     : 0;
    int b = (base + 2 * t + 1 < N) ? counts[base + 2 * t + 1] : 0;
    pairv[t] = a + b;
    buf[t]   = a + b;
    __syncthreads();
    for (int d = 1; d < 256; d <<= 1) {
        int v = buf[t];
        int w = (t >= d) ? buf[t - d] : 0;
        __syncthreads();
        buf[t] = v + w;
        __syncthreads();
    }
    int excl = buf[t] - pairv[t];
    if (base + 2 * t     < N) offsets[base + 2 * t]     = excl;
    if (base + 2 * t + 1 < N) offsets[base + 2 * t + 1] = excl + a;
    if (t == 255) partials[blockIdx.x] = buf[255];
}

__global__ void k_scan2(int* __restrict__ partials, int nblk) {
    __shared__ int buf[256];
    const int t = threadIdx.x;
    int v0 = (t < nblk) ? partials[t] : 0;
    buf[t] = v0;
    __syncthreads();
    for (int d = 1; d < 256; d <<= 1) {
        int v = buf[t];
        int w = (t >= d) ? buf[t - d] : 0;
        __syncthreads();
        buf[t] = v + w;
        __syncthreads();
    }
    if (t < nblk) partials[t] = buf[t] - v0;   // exclusive
}

__global__ __launch_bounds__(256) void k_scan3(
    int* __restrict__ offsets, const int* __restrict__ partials,
    int* __restrict__ cursor, int N)
{
    int i = blockIdx.x * 256 + threadIdx.x;
    if (i >= N) return;
    int v = offsets[i] + partials[i >> 9];
    offsets[i] = v;
    cursor[i]  = v;
}

__global__ __launch_bounds__(256) void k_scatter(
    const int* __restrict__ ei, const int* __restrict__ flag,
    int* __restrict__ cursor, int* __restrict__ csr_s,
    int* __restrict__ csr_r, int E)
{
    int e = blockIdx.x * 256 + threadIdx.x;
    if (e >= E) return;
    const int is64 = *flag;
    int s, r;
    if (is64) { s = ei[2 * e]; r = ei[2 * E + 2 * e]; }
    else      { s = ei[e];     r = ei[E + e];         }
    int slot = atomicAdd(&cursor[r], 1);
    csr_s[slot] = s;
    csr_r[slot] = r;
}

// ---- phase 1: AB[n][0:128]=bf16(x@W1a + b1), AB[n][128:256]=bf16(x@W1b) ----
__global__ __launch_bounds__(256) void k_node1(
    const float* __restrict__ x, const float* __restrict__ W1,
    const float* __restrict__ b1, __bf16* __restrict__ AB, int N, int ngroups)
{
    __shared__ __bf16 wt[256 * 128];
    for (int idx = threadIdx.x; idx < 256 * 128; idx += 256) {
        int j = idx & 255, k = idx >> 8;
        float w = (j < 128) ? W1[(k << 7) + j] : W1[((k + 128) << 7) + (j - 128)];
        wt[(j << 7) + ((((k >> 3) ^ (j & 7))) << 3) + (k & 7)] = (__bf16)w;
    }
    __syncthreads();

    const int lane = threadIdx.x & 63;
    const int row  = lane & 15;
    const int kq   = lane >> 4;

    for (int g = blockIdx.x; g < ngroups; g += gridDim.x) {
        const int row0 = g * 64 + (threadIdx.x >> 6) * 16;
        int m = row0 + row; if (m >= N) m = N - 1;
        const float* xr = x + (size_t)m * 128;

        bf16x8 afr[4];
#pragma unroll
        for (int c = 0; c < 4; ++c) {
            const int k0 = c * 32 + kq * 8;
            float4 a0 = *(const float4*)(xr + k0);
            float4 a1 = *(const float4*)(xr + k0 + 4);
            bf16x8 af;
            af[0]=(__bf16)a0.x; af[1]=(__bf16)a0.y; af[2]=(__bf16)a0.z; af[3]=(__bf16)a0.w;
            af[4]=(__bf16)a1.x; af[5]=(__bf16)a1.y; af[6]=(__bf16)a1.z; af[7]=(__bf16)a1.w;
            afr[c] = af;
        }

        f32x4 acc[16] = {};
#pragma unroll
        for (int t = 0; t < 16; ++t) {
            const int j  = t * 16 + row;
            const int jb = j & 7;
            const __bf16* base = wt + (j << 7);
#pragma unroll
            for (int c = 0; c < 4; ++c) {
                const int kb = c * 4 + kq;
                bf16x8 b = *(const bf16x8*)(base + ((kb ^ jb) << 3));
                acc[t] = MFMA16(afr[c], b, acc[t], 0, 0, 0);
            }
        }

#pragma unroll
        for (int t = 0; t < 16; ++t) {
            const int col = t * 16 + row;
            const float bb = (col < 128) ? b1[col] : 0.0f;
#pragma unroll
            for (int q = 0; q < 4; ++q) {
                const int gr = row0 + kq * 4 + q;
                if (gr < N) AB[(size_t)gr * 256 + col] = (__bf16)(acc[t][q] + bb);
            }
        }
    }
}

// ---- phase 2: edge-parallel over CSR-SORTED edges + run-merged atomics -----
// Edges sorted by receiver: B-row loads broadcast within runs; each lane owns
// 4 consecutive sorted edges -> merge equal-receiver runs before the atomic.
__global__ __launch_bounds__(256) void k_edge_sorted(
    const __bf16* __restrict__ AB, const float* __restrict__ pos,
    const int* __restrict__ csr_s, const int* __restrict__ csr_r,
    const float* __restrict__ W2, const float* __restrict__ b2,
    const float* __restrict__ w3, float* __restrict__ aggr, int E, int ngroups)
{
    __shared__ __bf16 wt[128 * 128];
    for (int idx = threadIdx.x; idx < 128 * 128; idx += 256) {
        int j = idx & 127, k = idx >> 7;
        wt[(j << 7) + ((((k >> 3) ^ (j & 7))) << 3) + (k & 7)] = (__bf16)W2[(k << 7) + j];
    }
    __syncthreads();

    const int lane = threadIdx.x & 63;
    const int row  = lane & 15;
    const int kq   = lane >> 4;

    float b2c[8];
#pragma unroll
    for (int t = 0; t < 8; ++t) b2c[t] = b2[t * 16 + row];

    for (int g = blockIdx.x; g < ngroups; g += gridDim.x) {
        const int e = g * 64 + (threadIdx.x >> 6) * 16 + row;
        const int s = csr_s[e];
        const int r = csr_r[e];

        float dx = pos[3 * s + 0] - pos[3 * r + 0];
        float dy = pos[3 * s + 1] - pos[3 * r + 1];
        float dz = pos[3 * s + 2] - pos[3 * r + 2];
        float d  = sqrtf(dx * dx + dy * dy + dz * dz);

        const __bf16* Arow = AB + (size_t)s * 256;
        const __bf16* Brow = AB + (size_t)r * 256 + 128;

        bf16x8 afr[4];
#pragma unroll
        for (int c = 0; c < 4; ++c) {
            const int k0 = c * 32 + kq * 8;
            bf16x8 av = *(const bf16x8*)(Arow + k0);
            bf16x8 bv = *(const bf16x8*)(Brow + k0);
            float4 w0 = *(const float4*)(w3 + k0);
            float4 w1 = *(const float4*)(w3 + k0 + 4);
            bf16x8 af;
            af[0] = (__bf16)silu_f((float)av[0] + (float)bv[0] + d * w0.x);
            af[1] = (__bf16)silu_f((float)av[1] + (float)bv[1] + d * w0.y);
            af[2] = (__bf16)silu_f((float)av[2] + (float)bv[2] + d * w0.z);
            af[3] = (__bf16)silu_f((float)av[3] + (float)bv[3] + d * w0.w);
            af[4] = (__bf16)silu_f((float)av[4] + (float)bv[4] + d * w1.x);
            af[5] = (__bf16)silu_f((float)av[5] + (float)bv[5] + d * w1.y);
            af[6] = (__bf16)silu_f((float)av[6] + (float)bv[6] + d * w1.z);
            af[7] = (__bf16)silu_f((float)av[7] + (float)bv[7] + d * w1.w);
            afr[c] = af;
        }

        f32x4 acc[8] = {};
#pragma unroll
        for (int t = 0; t < 8; ++t) {
            const int j  = t * 16 + row;
            const int jb = j & 7;
            const __bf16* base = wt + (j << 7);
#pragma unroll
            for (int c = 0; c < 4; ++c) {
                const int kb = c * 4 + kq;
                bf16x8 b = *(const bf16x8*)(base + ((kb ^ jb) << 3));
                acc[t] = MFMA16(afr[c], b, acc[t], 0, 0, 0);
            }
        }

        // receivers of this lane's 4 consecutive sorted edges (er = kq*4+q)
        int rr[4];
#pragma unroll
        for (int q = 0; q < 4; ++q) rr[q] = __shfl(r, kq * 4 + q, 64);

        // merge equal-receiver runs in-register, flush once per run
        float run[8];
#pragma unroll
        for (int t = 0; t < 8; ++t) run[t] = 0.0f;
        int curr = rr[0];
#pragma unroll
        for (int q = 0; q < 4; ++q) {
            if (rr[q] != curr) {
                float* dst = aggr + (size_t)curr * 128;
#pragma unroll
                for (int t = 0; t < 8; ++t) {
                    unsafeAtomicAdd(dst + t * 16 + row, run[t]);
                    run[t] = 0.0f;
                }
                curr = rr[q];
            }
#pragma unroll
            for (int t = 0; t < 8; ++t)
                run[t] += silu_f(acc[t][q] + b2c[t]);
        }
        {
            float* dst = aggr + (size_t)curr * 128;
#pragma unroll
            for (int t = 0; t < 8; ++t)
                unsafeAtomicAdd(dst + t * 16 + row, run[t]);
        }
    }
}

// ---- phase 2 fallback (round-3 atomic version, if ws too small) ------------
__global__ __launch_bounds__(256) void k_edge_fb(
    const __bf16* __restrict__ AB, const float* __restrict__ pos,
    const int* __restrict__ ei, const int* __restrict__ flag,
    const float* __restrict__ W2, const float* __restrict__ b2,
    const float* __restrict__ w3, float* __restrict__ aggr, int E, int ngroups)
{
    __shared__ __bf16 wt[128 * 128];
    for (int idx = threadIdx.x; idx < 128 * 128; idx += 256) {
        int j = idx & 127, k = idx >> 7;
        wt[(j << 7) + ((((k >> 3) ^ (j & 7))) << 3) + (k & 7)] = (__bf16)W2[(k << 7) + j];
    }
    __syncthreads();

    const int is64 = flag ? *flag : 0;
    const int lane = threadIdx.x & 63;
    const int row  = lane & 15;
    const int kq   = lane >> 4;

    for (int g = blockIdx.x; g < ngroups; g += gridDim.x) {
        const int e = g * 64 + (threadIdx.x >> 6) * 16 + row;
        int s, r;
        if (is64) { s = ei[2 * e]; r = ei[2 * E + 2 * e]; }
        else      { s = ei[e];     r = ei[E + e];         }
        float dx = pos[3 * s + 0] - pos[3 * r + 0];
        float dy = pos[3 * s + 1] - pos[3 * r + 1];
        float dz = pos[3 * s + 2] - pos[3 * r + 2];
        float d  = sqrtf(dx * dx + dy * dy + dz * dz);

        const __bf16* Arow = AB + (size_t)s * 256;
        const __bf16* Brow = AB + (size_t)r * 256 + 128;

        bf16x8 afr[4];
#pragma unroll
        for (int c = 0; c < 4; ++c) {
            const int k0 = c * 32 + kq * 8;
            bf16x8 av = *(const bf16x8*)(Arow + k0);
            bf16x8 bv = *(const bf16x8*)(Brow + k0);
            float4 w0 = *(const float4*)(w3 + k0);
            float4 w1 = *(const float4*)(w3 + k0 + 4);
            bf16x8 af;
            af[0] = (__bf16)silu_f((float)av[0] + (float)bv[0] + d * w0.x);
            af[1] = (__bf16)silu_f((float)av[1] + (float)bv[1] + d * w0.y);
            af[2] = (__bf16)silu_f((float)av[2] + (float)bv[2] + d * w0.z);
            af[3] = (__bf16)silu_f((float)av[3] + (float)bv[3] + d * w0.w);
            af[4] = (__bf16)silu_f((float)av[4] + (float)bv[4] + d * w1.x);
            af[5] = (__bf16)silu_f((float)av[5] + (float)bv[5] + d * w1.y);
            af[6] = (__bf16)silu_f((float)av[6] + (float)bv[6] + d * w1.z);
            af[7] = (__bf16)silu_f((float)av[7] + (float)bv[7] + d * w1.w);
            afr[c] = af;
        }

        f32x4 acc[8] = {};
#pragma unroll
        for (int t = 0; t < 8; ++t) {
            const int j  = t * 16 + row;
            const int jb = j & 7;
            const __bf16* base = wt + (j << 7);
#pragma unroll
            for (int c = 0; c < 4; ++c) {
                const int kb = c * 4 + kq;
                bf16x8 b = *(const bf16x8*)(base + ((kb ^ jb) << 3));
                acc[t] = MFMA16(afr[c], b, acc[t], 0, 0, 0);
            }
        }

        int rr[4];
#pragma unroll
        for (int q = 0; q < 4; ++q) rr[q] = __shfl(r, kq * 4 + q, 64);

#pragma unroll
        for (int t = 0; t < 8; ++t) {
            const int col = t * 16 + row;
            const float bb = b2[col];
#pragma unroll
            for (int q = 0; q < 4; ++q) {
                float v = silu_f(acc[t][q] + bb);
                unsafeAtomicAdd(aggr + (size_t)rr[q] * 128 + col, v);
            }
        }
    }
}

// -------- phase 3: u = silu(x@U1a + aggr@U1b + c1), bf16, IN PLACE over aggr
__global__ __launch_bounds__(256) void k_node2(
    const float* __restrict__ x, const float* __restrict__ aggr,
    const float* __restrict__ U1, const float* __restrict__ c1,
    __bf16* __restrict__ u, int N, int ngroups)
{
    __shared__ __bf16 wt[128 * 256];
    for (int idx = threadIdx.x; idx < 128 * 256; idx += 256) {
        int j = idx & 127, k = idx >> 7;
        wt[(j << 8) + ((((k >> 3) ^ (j & 7))) << 3) + (k & 7)] = (__bf16)U1[(k << 7) + j];
    }
    __syncthreads();

    const int lane = threadIdx.x & 63;
    const int row  = lane & 15;
    const int kq   = lane >> 4;

    for (int g = blockIdx.x; g < ngroups; g += gridDim.x) {
        const int row0 = g * 64 + (threadIdx.x >> 6) * 16;
        int m = row0 + row; if (m >= N) m = N - 1;

        bf16x8 afr[8];
#pragma unroll
        for (int c = 0; c < 8; ++c) {
            const int k0 = (c & 3) * 32 + kq * 8;
            const float* src = (c < 4) ? (x + (size_t)m * 128 + k0)
                                       : (aggr + (size_t)m * 128 + k0);
            float4 a0 = *(const float4*)(src);
            float4 a1 = *(const float4*)(src + 4);
            bf16x8 af;
            af[0]=(__bf16)a0.x; af[1]=(__bf16)a0.y; af[2]=(__bf16)a0.z; af[3]=(__bf16)a0.w;
            af[4]=(__bf16)a1.x; af[5]=(__bf16)a1.y; af[6]=(__bf16)a1.z; af[7]=(__bf16)a1.w;
            afr[c] = af;
        }

        f32x4 acc[8] = {};
#pragma unroll
        for (int t = 0; t < 8; ++t) {
            const int j  = t * 16 + row;
            const int jb = j & 7;
            const __bf16* base = wt + (j << 8);
#pragma unroll
            for (int c = 0; c < 8; ++c) {
                const int kb = c * 4 + kq;
                bf16x8 b = *(const bf16x8*)(base + ((kb ^ jb) << 3));
                acc[t] = MFMA16(afr[c], b, acc[t], 0, 0, 0);
            }
        }

#pragma unroll
        for (int t = 0; t < 8; ++t) {
            const int col = t * 16 + row;
            const float cc = c1[col];
#pragma unroll
            for (int q = 0; q < 4; ++q) {
                const int gr = row0 + kq * 4 + q;
                if (gr < N) u[(size_t)gr * 256 + col] = (__bf16)silu_f(acc[t][q] + cc);
            }
        }
    }
}

// ---------------- phase 4: out = u@U2 + c2 (overwrites AB in d_out) ---------
__global__ __launch_bounds__(256) void k_node3(
    const __bf16* __restrict__ u, const float* __restrict__ U2,
    const float* __restrict__ c2, float* __restrict__ out, int N, int ngroups)
{
    __shared__ __bf16 wt[128 * 128];
    for (int idx = threadIdx.x; idx < 128 * 128; idx += 256) {
        int j = idx & 127, k = idx >> 7;
        wt[(j << 7) + ((((k >> 3) ^ (j & 7))) << 3) + (k & 7)] = (__bf16)U2[(k << 7) + j];
    }
    __syncthreads();

    const int lane = threadIdx.x & 63;
    const int row  = lane & 15;
    const int kq   = lane >> 4;

    for (int g = blockIdx.x; g < ngroups; g += gridDim.x) {
        const int row0 = g * 64 + (threadIdx.x >> 6) * 16;
        int m = row0 + row; if (m >= N) m = N - 1;

        bf16x8 afr[4];
#pragma unroll
        for (int c = 0; c < 4; ++c) {
            const int k0 = c * 32 + kq * 8;
            afr[c] = *(const bf16x8*)(u + (size_t)m * 256 + k0);
        }

        f32x4 acc[8] = {};
#pragma unroll
        for (int t = 0; t < 8; ++t) {
            const int j  = t * 16 + row;
            const int jb = j & 7;
            const __bf16* base = wt + (j << 7);
#pragma unroll
            for (int c = 0; c < 4; ++c) {
                const int kb = c * 4 + kq;
                bf16x8 b = *(const bf16x8*)(base + ((kb ^ jb) << 3));
                acc[t] = MFMA16(afr[c], b, acc[t], 0, 0, 0);
            }
        }

#pragma unroll
        for (int t = 0; t < 8; ++t) {
            const int col = t * 16 + row;
            const float cc = c2[col];
#pragma unroll
            for (int q = 0; q < 4; ++q) {
                const int gr = row0 + kq * 4 + q;
                if (gr < N) out[(size_t)gr * 128 + col] = acc[t][q] + cc;
            }
        }
    }
}

extern "C" void kernel_launch(void* const* d_in, const int* in_sizes, int n_in,
                              void* d_out, int out_size, void* d_ws, size_t ws_size,
                              hipStream_t stream) {
    (void)n_in; (void)out_size;
    const float* x   = (const float*)d_in[0];
    const float* pos = (const float*)d_in[1];
    const int*   ei  = (const int*)d_in[2];
    const float* W1  = (const float*)d_in[3];
    const float* b1  = (const float*)d_in[4];
    const float* W2  = (const float*)d_in[5];
    const float* b2  = (const float*)d_in[6];
    const float* U1  = (const float*)d_in[7];
    const float* c1  = (const float*)d_in[8];
    const float* U2  = (const float*)d_in[9];
    const float* c2  = (const float*)d_in[10];

    const int N = in_sizes[0] / 128;
    const int E = in_sizes[2] / 2;

    // ---- workspace layout (16B-aligned slabs) ----
    const size_t aggr_b  = (size_t)N * 128 * sizeof(float);
    const size_t Ni_b    = (((size_t)N * 4) + 15) & ~(size_t)15;
    const size_t E_b     = (((size_t)E * 4) + 15) & ~(size_t)15;
    size_t off = 0;
    char* base = (char*)d_ws;
    float* aggr   = (float*)(base + off); off += aggr_b;
    int*   flag   = (int*)  (base + off); off += 16;
    int*   counts = (int*)  (base + off); off += Ni_b;
    int*   offs   = (int*)  (base + off); off += Ni_b;
    int*   cursor = (int*)  (base + off); off += Ni_b;
    int*   parts  = (int*)  (base + off); off += 256 * 4;
    int*   csr_s  = (int*)  (base + off); off += E_b;
    int*   csr_r  = (int*)  (base + off); off += E_b;
    const size_t need_csr = off;

    __bf16* u  = (__bf16*)d_ws;        // row stride 256 elem, aliases aggr
    __bf16* AB = (__bf16*)d_out;       // N*256 bf16 == out_nbytes

    const int nblk_scan = (N + 511) / 512;
    const bool csr_ok = (ws_size >= need_csr) && (nblk_scan <= 256);

    if (ws_size < aggr_b + 16) return;   // cannot run at all

    const int ng_nodes = (N + 63) / 64;
    const int grid_n   = ng_nodes < 512 ? ng_nodes : 512;
    const int grid_E   = (E + 255) / 256;
    const int grid_Nt  = (N + 255) / 256;
    const int ng_edges = E / 64;
    const int grid_e   = ng_edges < 1250 ? ng_edges : 1250;

    k_detect<<<1, 256, 0, stream>>>(ei, flag);
    k_node1<<<grid_n, 256, 0, stream>>>(x, W1, b1, AB, N, ng_nodes);
    hipMemsetAsync(aggr, 0, aggr_b, stream);

    if (csr_ok) {
        hipMemsetAsync(counts, 0, (size_t)N * 4, stream);
        k_hist   <<<grid_E, 256, 0, stream>>>(ei, flag, counts, E);
        k_scan1  <<<nblk_scan, 256, 0, stream>>>(counts, offs, parts, N);
        k_scan2  <<<1, 256, 0, stream>>>(parts, nblk_scan);
        k_scan3  <<<grid_Nt, 256, 0, stream>>>(offs, parts, cursor, N);
        k_scatter<<<grid_E, 256, 0, stream>>>(ei, flag, cursor, csr_s, csr_r, E);
        k_edge_sorted<<<grid_e, 256, 0, stream>>>(
            AB, pos, csr_s, csr_r, W2, b2, W1 + 256 * 128, aggr, E, ng_edges);
    } else {
        k_edge_fb<<<grid_e, 256, 0, stream>>>(AB, pos, ei, flag, W2, b2,
                                              W1 + 256 * 128, aggr, E, ng_edges);
    }

    k_node2<<<grid_n, 256, 0, stream>>>(x, aggr, U1, c1, u, N, ng_nodes);
    k_node3<<<grid_n, 256, 0, stream>>>(u, U2, c2, (float*)d_out, N, ng_nodes);
}